// Round 3
// baseline (1853.439 us; speedup 1.0000x reference)
//
#include <hip/hip_runtime.h>
#include <math.h>

// HeterogeneousGNN fused kernel for MI355X (gfx950) — round 3.
// One WG (512 thr = 8 waves) per batch element; H[b] (256x128 bf16, swizzled)
// resident in LDS across all 3 layers. Per layer, per half h, per v-chunk of
// 64: GEMM1 (Gc = H @ W^T, one 32x32 MFMA tile/wave) -> Gc^T in LDS; GEMM2
// (acc += A_h @ Gc, 64x64 tile/wave, acc[2][2] f32x16). All MFMA are
// 32x32x16_bf16 (halves LDS traffic/FLOP vs 16x16x32). A (sigmoid-masked,
// neg sign folded) and W are pre-swizzled into MFMA fragment order by prep ->
// all global frag reads are contiguous 1KB/wave from L2. Register budget:
// acc 64 + gacc 16 + frags ~16 + addr ~20 = ~116 < 128 cap (launch_bounds
// (512,2)) -> NO SPILLS (rounds 1-2 failure: 2-4 GB scratch traffic).
// LDS = H 64K + Gc 16K = 80 KB -> 2 blocks/CU.

typedef float  f32x4  __attribute__((ext_vector_type(4)));
typedef float  f32x16 __attribute__((ext_vector_type(16)));
typedef short  s16x8  __attribute__((ext_vector_type(8)));
typedef __bf16 bf16x8 __attribute__((ext_vector_type(8)));

#define NNODE 256
#define DIMF  128
#define HB    65536   // byte offset of Gc region in LDS

__device__ __forceinline__ unsigned short f2bf(float f) {
  unsigned int u = __builtin_bit_cast(unsigned int, f);
  u = (u + 0x7fffu + ((u >> 16) & 1u)) >> 16;   // round-to-nearest-even
  return (unsigned short)u;
}
__device__ __forceinline__ float bf2f(unsigned short h) {
  return __builtin_bit_cast(float, (unsigned int)h << 16);
}

// H: [256 v][128 d] bf16. Row = 256 B = 16 slots of 16 B; XOR by (v&15) makes
// the 32-row-stride column read 2-way (free) instead of 16-way.
__device__ __forceinline__ int haddr(int v, int d) {
  return v * 256 + ((d * 2) ^ ((v & 15) << 4));
}
// Gc^T: [128 o][64 v] bf16. Row = 128 B = 8 slots; XOR by (o&7) -> 4-way
// (b128 floor for same-column reads).
__device__ __forceinline__ int gaddr(int o, int vr) {
  return HB + o * 128 + ((vr * 2) ^ ((o & 7) << 4));
}

#define MFMA32(a, b, c) __builtin_amdgcn_mfma_f32_32x32x16_bf16( \
    __builtin_bit_cast(bf16x8, (a)), __builtin_bit_cast(bf16x8, (b)), (c), 0, 0, 0)

// ---- prep: build fragment-ordered A3 and W3 (bf16) ----
// A3[h][ut 0..7][vt 0..15][lane 0..63][j 0..7] = Ac_h[u = ut*32+(lane&31)]
//                                                  [v = vt*16+(lane>>5)*8+j]
// W3[hw 0..5][ot 0..3][kt 0..7][lane][j]       = W_hw[o = ot*32+(lane&31)]
//                                                  [d = kt*16+(lane>>5)*8+j]
__global__ void prep_kernel(const float* __restrict__ alp, const float* __restrict__ aln,
                            const float* __restrict__ wp,  const float* __restrict__ wn,
                            unsigned short* __restrict__ A3, unsigned short* __restrict__ W3) {
  int idx = blockIdx.x * 512 + threadIdx.x;     // 229376 threads total
  if (idx < 131072) {
    int j = idx & 7, lane = (idx >> 3) & 63, vt = (idx >> 9) & 15,
        ut = (idx >> 13) & 7, h = (idx >> 16) & 1;
    int u = ut * 32 + (lane & 31);
    int v = vt * 16 + (lane >> 5) * 8 + j;
    int s = u * 256 + v;
    float ap = 1.f / (1.f + expf(-alp[s]));
    float an = 1.f / (1.f + expf(-aln[s]));
    bool  m  = ap > an;
    float val = h ? (m ? 0.f : -an) : (m ? ap : 0.f);   // neg sign folded
    A3[idx] = f2bf(val);
  } else {
    int k = idx - 131072;                       // 0 .. 98303
    int j = k & 7, lane = (k >> 3) & 63, kt = (k >> 9) & 7,
        ot = (k >> 12) & 3, hw = (k >> 14);     // hw = l*2+h, 0..5
    int o = ot * 32 + (lane & 31);
    int d = kt * 16 + (lane >> 5) * 8 + j;
    const float* src = (hw & 1) ? wn : wp;
    W3[k] = f2bf(src[(hw >> 1) * 16384 + o * 128 + d]);
  }
}

__global__ __launch_bounds__(512, 2) void gnn_kernel(
    const float* __restrict__ X,
    const unsigned short* __restrict__ A3,
    const unsigned short* __restrict__ W3,
    const float* __restrict__ ln_g, const float* __restrict__ ln_b,
    const float* __restrict__ ro_g, const float* __restrict__ ro_b,
    float* __restrict__ out) {
  extern __shared__ char smem[];
  const int tid  = threadIdx.x;
  const int wid  = tid >> 6;
  const int lane = tid & 63;
  const int l31  = lane & 31;
  const int hi   = lane >> 5;
  const int b    = blockIdx.x;
  const int rg1  = wid >> 2, cg1 = wid & 3;    // GEMM1: v-tile(32), o-tile(32)
  const int rg2  = wid >> 1, cg2 = wid & 1;    // GEMM2: u-group(64), o-group(64)

  // ---- stage H = bf16(X[b]) into LDS ----
  {
    const float4* Xb = (const float4*)(X + (size_t)b * NNODE * DIMF);
#pragma unroll
    for (int i = 0; i < 16; ++i) {
      int idx = tid + i * 512;                 // 8192 float4 chunks
      int v = idx >> 5, d = (idx & 31) * 4;
      float4 f = Xb[idx];
      ushort4 p;
      p.x = f2bf(f.x); p.y = f2bf(f.y); p.z = f2bf(f.z); p.w = f2bf(f.w);
      *(ushort4*)(smem + haddr(v, d)) = p;
    }
  }
  __syncthreads();

  f32x16 acc[2][2];
  for (int l = 0; l < 3; ++l) {
#pragma unroll
    for (int mt = 0; mt < 2; ++mt)
#pragma unroll
      for (int nt = 0; nt < 2; ++nt)
#pragma unroll
        for (int r = 0; r < 16; ++r) acc[mt][nt][r] = 0.f;

    for (int h = 0; h < 2; ++h) {
      const unsigned short* Wf = W3 + (((l * 2 + h) * 4 + cg1) * 8) * 512;
      for (int c = 0; c < 4; ++c) {
        // ---- GEMM1: Gc[v in 64c..][o] = H @ W^T; one 32x32 tile per wave ----
        f32x16 gacc;
#pragma unroll
        for (int r = 0; r < 16; ++r) gacc[r] = 0.f;
        const int v0 = c * 64 + rg1 * 32 + l31;
#pragma unroll
        for (int kt = 0; kt < 8; ++kt) {       // K = d = 128
          s16x8 ha = *(const s16x8*)(smem + haddr(v0, kt * 16 + hi * 8));
          s16x8 wb = *(const s16x8*)(Wf + kt * 512 + lane * 8);
          gacc = MFMA32(ha, wb, gacc);
        }
        __syncthreads();                       // prev GEMM2 done reading Gc
        {
          const int og = cg1 * 32 + l31;       // C/D col = lane&31
#pragma unroll
          for (int rq = 0; rq < 4; ++rq) {     // rows v = (r&3)+8*(r>>2)+4*hi
            int vr = rg1 * 32 + rq * 8 + hi * 4;
            ushort4 p;
            p.x = f2bf(gacc[rq * 4 + 0]);
            p.y = f2bf(gacc[rq * 4 + 1]);
            p.z = f2bf(gacc[rq * 4 + 2]);
            p.w = f2bf(gacc[rq * 4 + 3]);
            *(ushort4*)(smem + gaddr(og, vr)) = p;
          }
        }
        __syncthreads();

        // ---- GEMM2: acc += Ac_h[u, 64c..] @ Gc; 64x64 tile per wave ----
#pragma unroll
        for (int kt = 0; kt < 4; ++kt) {       // K = v-chunk = 64
          s16x8 b0 = *(const s16x8*)(smem + gaddr(cg2 * 64 + l31,      kt * 16 + hi * 8));
          s16x8 b1 = *(const s16x8*)(smem + gaddr(cg2 * 64 + 32 + l31, kt * 16 + hi * 8));
          s16x8 a0 = *(const s16x8*)(A3 + (size_t)(((h * 8 + rg2 * 2 + 0) * 16) + c * 4 + kt) * 512 + lane * 8);
          s16x8 a1 = *(const s16x8*)(A3 + (size_t)(((h * 8 + rg2 * 2 + 1) * 16) + c * 4 + kt) * 512 + lane * 8);
          acc[0][0] = MFMA32(a0, b0, acc[0][0]);
          acc[0][1] = MFMA32(a0, b1, acc[0][1]);
          acc[1][0] = MFMA32(a1, b0, acc[1][0]);
          acc[1][1] = MFMA32(a1, b1, acc[1][1]);
        }
      } // chunks
    } // halves

    // ---- epilogue: exact GELU + LayerNorm -> H ----
    const float lg0 = ln_g[l * 128 + cg2 * 64 + l31];
    const float lg1 = ln_g[l * 128 + cg2 * 64 + 32 + l31];
    const float lb0 = ln_b[l * 128 + cg2 * 64 + l31];
    const float lb1 = ln_b[l * 128 + cg2 * 64 + 32 + l31];
#pragma unroll
    for (int mt = 0; mt < 2; ++mt)
#pragma unroll
      for (int nt = 0; nt < 2; ++nt)
#pragma unroll
        for (int r = 0; r < 16; ++r) {
          float x = acc[mt][nt][r];
          acc[mt][nt][r] = 0.5f * x * (1.f + erff(x * 0.70710678f));
        }
    __syncthreads();   // all waves' GEMM2 Gc reads done; Gc region reusable
    // per-row partials over this wave's 64 cols -> red4[u] (in dead Gc region)
    float w1 = 0.f, w2 = 0.f;
#pragma unroll
    for (int mt = 0; mt < 2; ++mt)
#pragma unroll
      for (int r = 0; r < 16; ++r) {
        float a0 = acc[mt][0][r], a1 = acc[mt][1][r];
        float s1 = a0 + a1;
        float s2 = a0 * a0 + a1 * a1;
#pragma unroll
        for (int m = 1; m < 32; m <<= 1) {     // reduce over 32 cols (in-half)
          s1 += __shfl_xor(s1, m);
          s2 += __shfl_xor(s2, m);
        }
        if (l31 == mt * 16 + r) { w1 = s1; w2 = s2; }
      }
    {
      int j  = l31;                            // j encodes (mt = j>>4, r = j&15)
      int uw = rg2 * 64 + (j >> 4) * 32 + (j & 3) + ((j >> 2) & 3) * 8 + hi * 4;
      float2 pw; pw.x = w1; pw.y = w2;
      *(float2*)(smem + HB + uw * 16 + cg2 * 8) = pw;
    }
    __syncthreads();
#pragma unroll
    for (int mt = 0; mt < 2; ++mt)
#pragma unroll
      for (int r = 0; r < 16; ++r) {
        int u = rg2 * 64 + mt * 32 + (r & 3) + ((r >> 2) & 3) * 8 + hi * 4;
        f32x4 rd = *(const f32x4*)(smem + HB + u * 16);    // broadcast read
        float mu  = (rd[0] + rd[2]) * (1.f / 128.f);
        float var = (rd[1] + rd[3]) * (1.f / 128.f) - mu * mu;
        float rs  = rsqrtf(var + 1e-5f);
        float y0 = (acc[mt][0][r] - mu) * rs * lg0 + lb0;
        float y1 = (acc[mt][1][r] - mu) * rs * lg1 + lb1;
        *(unsigned short*)(smem + haddr(u, cg2 * 64 + l31))      = f2bf(y0);
        *(unsigned short*)(smem + haddr(u, cg2 * 64 + 32 + l31)) = f2bf(y1);
      }
    __syncthreads();   // H fully updated before next layer / readout
  }

  // ---- readout: mean over nodes + final LN ----
  {
    int d   = tid & 127;
    int grp = tid >> 7;
    float s = 0.f;
    for (int v = grp * 64; v < grp * 64 + 64; ++v)
      s += bf2f(*(const unsigned short*)(smem + haddr(v, d)));
    float* red = (float*)(smem + HB);
    red[grp * 128 + d] = s;
    __syncthreads();
    if (tid < 128) {
      float hv = (red[tid] + red[128 + tid] + red[256 + tid] + red[384 + tid]) * (1.f / 256.f);
      red[512 + tid] = hv;
    }
    __syncthreads();
    if (tid < 64) {
      float a  = red[512 + tid];
      float b2 = red[512 + 64 + tid];
      float s1 = a + b2, s2 = a * a + b2 * b2;
#pragma unroll
      for (int m = 1; m < 64; m <<= 1) {
        s1 += __shfl_xor(s1, m);
        s2 += __shfl_xor(s2, m);
      }
      float mu  = s1 * (1.f / 128.f);
      float var = s2 * (1.f / 128.f) - mu * mu;
      float rs  = rsqrtf(var + 1e-5f);
      out[(size_t)b * 128 + tid]      = (a  - mu) * rs * ro_g[tid]      + ro_b[tid];
      out[(size_t)b * 128 + 64 + tid] = (b2 - mu) * rs * ro_g[64 + tid] + ro_b[64 + tid];
    }
  }
}

extern "C" void kernel_launch(void* const* d_in, const int* in_sizes, int n_in,
                              void* d_out, int out_size, void* d_ws, size_t ws_size,
                              hipStream_t stream) {
  const float* X   = (const float*)d_in[0];
  const float* alp = (const float*)d_in[1];
  const float* aln = (const float*)d_in[2];
  const float* wp  = (const float*)d_in[3];
  const float* wn  = (const float*)d_in[4];
  const float* lng = (const float*)d_in[5];
  const float* lnb = (const float*)d_in[6];
  const float* rog = (const float*)d_in[7];
  const float* rob = (const float*)d_in[8];
  float* out = (float*)d_out;

  unsigned short* A3 = (unsigned short*)d_ws;          // 131072 bf16 = 256 KB
  unsigned short* W3 = A3 + 131072;                    //  98304 bf16 = 192 KB

  (void)hipFuncSetAttribute(reinterpret_cast<const void*>(gnn_kernel),
                            hipFuncAttributeMaxDynamicSharedMemorySize, 81920);

  prep_kernel<<<448, 512, 0, stream>>>(alp, aln, wp, wn, A3, W3);
  gnn_kernel<<<2048, 512, 81920, stream>>>(X, A3, W3, lng, lnb, rog, rob, out);
}

// Round 4
// 1508.210 us; speedup vs baseline: 1.2289x; 1.2289x over previous
//
#include <hip/hip_runtime.h>
#include <math.h>

// HeterogeneousGNN fused kernel for MI355X (gfx950) — round 4.
// Structure as round 3 (H resident in LDS, chunked Gc, 32x32x16 MFMA,
// fragment-preswizzled A/W in d_ws). Round-3 failure: fully-unrolled K-loops
// let the scheduler hoist all frag loads (64 extra VGPRs) -> allocator spilled
// acc to meet its 128-reg occupancy target -> 3.8 GB scratch traffic. Fix:
// unroll<=2 + sched_barrier(0) per iteration pins peak pressure at ~110 regs.

typedef float  f32x4  __attribute__((ext_vector_type(4)));
typedef float  f32x16 __attribute__((ext_vector_type(16)));
typedef short  s16x8  __attribute__((ext_vector_type(8)));
typedef __bf16 bf16x8 __attribute__((ext_vector_type(8)));

#define NNODE 256
#define DIMF  128
#define HB    65536   // byte offset of Gc region in LDS

__device__ __forceinline__ unsigned short f2bf(float f) {
  unsigned int u = __builtin_bit_cast(unsigned int, f);
  u = (u + 0x7fffu + ((u >> 16) & 1u)) >> 16;   // round-to-nearest-even
  return (unsigned short)u;
}
__device__ __forceinline__ float bf2f(unsigned short h) {
  return __builtin_bit_cast(float, (unsigned int)h << 16);
}

// H: [256 v][128 d] bf16; XOR by (v&15) -> column reads 2-way (free).
__device__ __forceinline__ int haddr(int v, int d) {
  return v * 256 + ((d * 2) ^ ((v & 15) << 4));
}
// Gc^T: [128 o][64 v] bf16; XOR by (o&7) -> 2-way on 16-lane groups.
__device__ __forceinline__ int gaddr(int o, int vr) {
  return HB + o * 128 + ((vr * 2) ^ ((o & 7) << 4));
}

#define MFMA32(a, b, c) __builtin_amdgcn_mfma_f32_32x32x16_bf16( \
    __builtin_bit_cast(bf16x8, (a)), __builtin_bit_cast(bf16x8, (b)), (c), 0, 0, 0)

// ---- prep: build fragment-ordered A3 and W3 (bf16) ----
// A3[h][ut 0..7][vt 0..15][lane][j] = Ac_h[u=ut*32+(lane&31)][v=vt*16+(lane>>5)*8+j]
// W3[hw 0..5][ot 0..3][kt 0..7][lane][j] = W_hw[o=ot*32+(lane&31)][d=kt*16+(lane>>5)*8+j]
__global__ void prep_kernel(const float* __restrict__ alp, const float* __restrict__ aln,
                            const float* __restrict__ wp,  const float* __restrict__ wn,
                            unsigned short* __restrict__ A3, unsigned short* __restrict__ W3) {
  int idx = blockIdx.x * 512 + threadIdx.x;     // 229376 threads total
  if (idx < 131072) {
    int j = idx & 7, lane = (idx >> 3) & 63, vt = (idx >> 9) & 15,
        ut = (idx >> 13) & 7, h = (idx >> 16) & 1;
    int u = ut * 32 + (lane & 31);
    int v = vt * 16 + (lane >> 5) * 8 + j;
    int s = u * 256 + v;
    float ap = 1.f / (1.f + expf(-alp[s]));
    float an = 1.f / (1.f + expf(-aln[s]));
    bool  m  = ap > an;
    float val = h ? (m ? 0.f : -an) : (m ? ap : 0.f);   // neg sign folded
    A3[idx] = f2bf(val);
  } else {
    int k = idx - 131072;                       // 0 .. 98303
    int j = k & 7, lane = (k >> 3) & 63, kt = (k >> 9) & 7,
        ot = (k >> 12) & 3, hw = (k >> 14);     // hw = l*2+h
    int o = ot * 32 + (lane & 31);
    int d = kt * 16 + (lane >> 5) * 8 + j;
    const float* src = (hw & 1) ? wn : wp;
    W3[k] = f2bf(src[(hw >> 1) * 16384 + o * 128 + d]);
  }
}

__global__ __launch_bounds__(512, 2) void gnn_kernel(
    const float* __restrict__ X,
    const unsigned short* __restrict__ A3,
    const unsigned short* __restrict__ W3,
    const float* __restrict__ ln_g, const float* __restrict__ ln_b,
    const float* __restrict__ ro_g, const float* __restrict__ ro_b,
    float* __restrict__ out) {
  extern __shared__ char smem[];
  const int tid  = threadIdx.x;
  const int wid  = tid >> 6;
  const int lane = tid & 63;
  const int l31  = lane & 31;
  const int hi   = lane >> 5;
  const int b    = blockIdx.x;
  const int rg1  = wid >> 2, cg1 = wid & 3;    // GEMM1: v-tile(32), o-tile(32)
  const int rg2  = wid >> 1, cg2 = wid & 1;    // GEMM2: u-group(64), o-group(64)

  // ---- stage H = bf16(X[b]) into LDS ----
  {
    const float4* Xb = (const float4*)(X + (size_t)b * NNODE * DIMF);
#pragma unroll
    for (int i = 0; i < 16; ++i) {
      int idx = tid + i * 512;                 // 8192 float4 chunks
      int v = idx >> 5, d = (idx & 31) * 4;
      float4 f = Xb[idx];
      ushort4 p;
      p.x = f2bf(f.x); p.y = f2bf(f.y); p.z = f2bf(f.z); p.w = f2bf(f.w);
      *(ushort4*)(smem + haddr(v, d)) = p;
    }
  }
  __syncthreads();

  f32x16 acc[2][2];
  for (int l = 0; l < 3; ++l) {
#pragma unroll
    for (int mt = 0; mt < 2; ++mt)
#pragma unroll
      for (int nt = 0; nt < 2; ++nt)
#pragma unroll
        for (int r = 0; r < 16; ++r) acc[mt][nt][r] = 0.f;

    for (int h = 0; h < 2; ++h) {
      const unsigned short* Wf  = W3 + (((l * 2 + h) * 4 + cg1) * 8) * 512;
      const unsigned short* Ab0 = A3 + (size_t)((h * 8 + rg2 * 2 + 0) * 16) * 512;
      const unsigned short* Ab1 = A3 + (size_t)((h * 8 + rg2 * 2 + 1) * 16) * 512;

      for (int c = 0; c < 4; ++c) {
        // ---- GEMM1: Gc[v in 64c..][o] = H @ W^T; one 32x32 tile per wave ----
        f32x16 gacc;
#pragma unroll
        for (int r = 0; r < 16; ++r) gacc[r] = 0.f;
        const int v0 = c * 64 + rg1 * 32 + l31;
#pragma unroll 2
        for (int kt = 0; kt < 8; ++kt) {       // K = d = 128
          s16x8 ha = *(const s16x8*)(smem + haddr(v0, kt * 16 + hi * 8));
          s16x8 wb = *(const s16x8*)(Wf + kt * 512 + lane * 8);
          gacc = MFMA32(ha, wb, gacc);
          __builtin_amdgcn_sched_barrier(0);   // no cross-iter load hoisting
        }
        __syncthreads();                       // prev GEMM2 done reading Gc
        {
          const int og = cg1 * 32 + l31;       // C/D col = lane&31
#pragma unroll
          for (int rq = 0; rq < 4; ++rq) {     // rows v = (r&3)+8*(r>>2)+4*hi
            int vr = rg1 * 32 + rq * 8 + hi * 4;
            ushort4 p;
            p.x = f2bf(gacc[rq * 4 + 0]);
            p.y = f2bf(gacc[rq * 4 + 1]);
            p.z = f2bf(gacc[rq * 4 + 2]);
            p.w = f2bf(gacc[rq * 4 + 3]);
            *(ushort4*)(smem + gaddr(og, vr)) = p;
          }
        }
        __syncthreads();

        // ---- GEMM2: acc += Ac_h[u, 64c..] @ Gc; 64x64 tile per wave ----
#pragma unroll 1
        for (int kt = 0; kt < 4; ++kt) {       // K = v-chunk = 64
          s16x8 b0 = *(const s16x8*)(smem + gaddr(cg2 * 64 + l31,      kt * 16 + hi * 8));
          s16x8 b1 = *(const s16x8*)(smem + gaddr(cg2 * 64 + 32 + l31, kt * 16 + hi * 8));
          s16x8 a0 = *(const s16x8*)(Ab0 + (c * 4 + kt) * 512 + lane * 8);
          s16x8 a1 = *(const s16x8*)(Ab1 + (c * 4 + kt) * 512 + lane * 8);
          acc[0][0] = MFMA32(a0, b0, acc[0][0]);
          acc[0][1] = MFMA32(a0, b1, acc[0][1]);
          acc[1][0] = MFMA32(a1, b0, acc[1][0]);
          acc[1][1] = MFMA32(a1, b1, acc[1][1]);
          __builtin_amdgcn_sched_barrier(0);   // no cross-iter load hoisting
        }
      } // chunks
    } // halves

    // ---- epilogue: exact GELU + LayerNorm -> H ----
    const float lg0 = ln_g[l * 128 + cg2 * 64 + l31];
    const float lg1 = ln_g[l * 128 + cg2 * 64 + 32 + l31];
    const float lb0 = ln_b[l * 128 + cg2 * 64 + l31];
    const float lb1 = ln_b[l * 128 + cg2 * 64 + 32 + l31];
#pragma unroll
    for (int mt = 0; mt < 2; ++mt)
#pragma unroll
      for (int nt = 0; nt < 2; ++nt)
#pragma unroll
        for (int r = 0; r < 16; ++r) {
          float x = acc[mt][nt][r];
          acc[mt][nt][r] = 0.5f * x * (1.f + erff(x * 0.70710678f));
        }
    __syncthreads();   // all waves' GEMM2 Gc reads done; Gc region reusable
    // per-row partials over this wave's 64 cols -> (sum, sumsq) in dead Gc region
    float w1 = 0.f, w2 = 0.f;
#pragma unroll
    for (int mt = 0; mt < 2; ++mt)
#pragma unroll
      for (int r = 0; r < 16; ++r) {
        float a0 = acc[mt][0][r], a1 = acc[mt][1][r];
        float s1 = a0 + a1;
        float s2 = a0 * a0 + a1 * a1;
#pragma unroll
        for (int m = 1; m < 32; m <<= 1) {     // reduce over 32 cols (in-half)
          s1 += __shfl_xor(s1, m);
          s2 += __shfl_xor(s2, m);
        }
        if (l31 == mt * 16 + r) { w1 = s1; w2 = s2; }
      }
    {
      int j  = l31;                            // j encodes (mt = j>>4, r = j&15)
      int uw = rg2 * 64 + (j >> 4) * 32 + (j & 3) + ((j >> 2) & 3) * 8 + hi * 4;
      float2 pw; pw.x = w1; pw.y = w2;
      *(float2*)(smem + HB + uw * 16 + cg2 * 8) = pw;
    }
    __syncthreads();
#pragma unroll
    for (int mt = 0; mt < 2; ++mt)
#pragma unroll
      for (int r = 0; r < 16; ++r) {
        int u = rg2 * 64 + mt * 32 + (r & 3) + ((r >> 2) & 3) * 8 + hi * 4;
        f32x4 rd = *(const f32x4*)(smem + HB + u * 16);    // broadcast read
        float mu  = (rd[0] + rd[2]) * (1.f / 128.f);
        float var = (rd[1] + rd[3]) * (1.f / 128.f) - mu * mu;
        float rs  = rsqrtf(var + 1e-5f);
        float y0 = (acc[mt][0][r] - mu) * rs * lg0 + lb0;
        float y1 = (acc[mt][1][r] - mu) * rs * lg1 + lb1;
        *(unsigned short*)(smem + haddr(u, cg2 * 64 + l31))      = f2bf(y0);
        *(unsigned short*)(smem + haddr(u, cg2 * 64 + 32 + l31)) = f2bf(y1);
      }
    __syncthreads();   // H fully updated before next layer / readout
  }

  // ---- readout: mean over nodes + final LN ----
  {
    int d   = tid & 127;
    int grp = tid >> 7;
    float s = 0.f;
    for (int v = grp * 64; v < grp * 64 + 64; ++v)
      s += bf2f(*(const unsigned short*)(smem + haddr(v, d)));
    float* red = (float*)(smem + HB);
    red[grp * 128 + d] = s;
    __syncthreads();
    if (tid < 128) {
      float hv = (red[tid] + red[128 + tid] + red[256 + tid] + red[384 + tid]) * (1.f / 256.f);
      red[512 + tid] = hv;
    }
    __syncthreads();
    if (tid < 64) {
      float a  = red[512 + tid];
      float b2 = red[512 + 64 + tid];
      float s1 = a + b2, s2 = a * a + b2 * b2;
#pragma unroll
      for (int m = 1; m < 64; m <<= 1) {
        s1 += __shfl_xor(s1, m);
        s2 += __shfl_xor(s2, m);
      }
      float mu  = s1 * (1.f / 128.f);
      float var = s2 * (1.f / 128.f) - mu * mu;
      float rs  = rsqrtf(var + 1e-5f);
      out[(size_t)b * 128 + tid]      = (a  - mu) * rs * ro_g[tid]      + ro_b[tid];
      out[(size_t)b * 128 + 64 + tid] = (b2 - mu) * rs * ro_g[64 + tid] + ro_b[64 + tid];
    }
  }
}

extern "C" void kernel_launch(void* const* d_in, const int* in_sizes, int n_in,
                              void* d_out, int out_size, void* d_ws, size_t ws_size,
                              hipStream_t stream) {
  const float* X   = (const float*)d_in[0];
  const float* alp = (const float*)d_in[1];
  const float* aln = (const float*)d_in[2];
  const float* wp  = (const float*)d_in[3];
  const float* wn  = (const float*)d_in[4];
  const float* lng = (const float*)d_in[5];
  const float* lnb = (const float*)d_in[6];
  const float* rog = (const float*)d_in[7];
  const float* rob = (const float*)d_in[8];
  float* out = (float*)d_out;

  unsigned short* A3 = (unsigned short*)d_ws;          // 131072 bf16 = 256 KB
  unsigned short* W3 = A3 + 131072;                    //  98304 bf16 = 192 KB

  (void)hipFuncSetAttribute(reinterpret_cast<const void*>(gnn_kernel),
                            hipFuncAttributeMaxDynamicSharedMemorySize, 81920);

  prep_kernel<<<448, 512, 0, stream>>>(alp, aln, wp, wn, A3, W3);
  gnn_kernel<<<2048, 512, 81920, stream>>>(X, A3, W3, lng, lnb, rog, rob, out);
}

// Round 5
// 1235.407 us; speedup vs baseline: 1.5003x; 1.2208x over previous
//
#include <hip/hip_runtime.h>
#include <math.h>

// HeterogeneousGNN fused kernel for MI355X (gfx950) — round 5.
// Structure: H[b] resident in LDS; per (layer, half): W frags hoisted to regs,
// Gc computed per 64-node chunk into a DOUBLE-BUFFERED 32KB LDS region (one
// barrier per chunk), GEMM2 accumulates acc[2][2] f32x16. Round-4 diagnosis:
// allocator targeted 128 VGPR (4 waves/EU) and spilled acc (~400 MB scratch,
// ~500cyc stalls per MFMA); sched_barrier(0) killed ILP. Fix: pin
// amdgpu_waves_per_eu(2,2) -> 256-reg budget (demand ~196, zero spills), full
// unroll, no sched barriers -> compiler software-pipelines loads.

typedef float  f32x4  __attribute__((ext_vector_type(4)));
typedef float  f32x16 __attribute__((ext_vector_type(16)));
typedef short  s16x8  __attribute__((ext_vector_type(8)));
typedef __bf16 bf16x8 __attribute__((ext_vector_type(8)));

#define NNODE 256
#define DIMF  128
#define HB    65536   // byte offset of Gc region in LDS (2 x 32768)

__device__ __forceinline__ unsigned short f2bf(float f) {
  unsigned int u = __builtin_bit_cast(unsigned int, f);
  u = (u + 0x7fffu + ((u >> 16) & 1u)) >> 16;   // round-to-nearest-even
  return (unsigned short)u;
}
__device__ __forceinline__ float bf2f(unsigned short h) {
  return __builtin_bit_cast(float, (unsigned int)h << 16);
}

// H: [256 v][128 d] bf16; XOR by (v&15) -> column reads 2-way (free).
__device__ __forceinline__ int haddr(int v, int d) {
  return v * 256 + ((d * 2) ^ ((v & 15) << 4));
}
// Gc^T: [128 o][row 256 B (64 v used)] bf16, double-buffered; 16-slot XOR by
// (o&15) -> column reads 2-way (free).
__device__ __forceinline__ int gaddr(int o, int vr, int buf) {
  return HB + buf * 32768 + o * 256 + ((vr * 2) ^ ((o & 15) << 4));
}

#define MFMA32(a, b, c) __builtin_amdgcn_mfma_f32_32x32x16_bf16( \
    __builtin_bit_cast(bf16x8, (a)), __builtin_bit_cast(bf16x8, (b)), (c), 0, 0, 0)

// ---- prep: build fragment-ordered A3 and W3 (bf16) ----
// A3[h][ut 0..7][vt 0..15][lane][j] = Ac_h[u=ut*32+(lane&31)][v=vt*16+(lane>>5)*8+j]
// W3[hw 0..5][ot 0..3][kt 0..7][lane][j] = W_hw[o=ot*32+(lane&31)][d=kt*16+(lane>>5)*8+j]
__global__ void prep_kernel(const float* __restrict__ alp, const float* __restrict__ aln,
                            const float* __restrict__ wp,  const float* __restrict__ wn,
                            unsigned short* __restrict__ A3, unsigned short* __restrict__ W3) {
  int idx = blockIdx.x * 512 + threadIdx.x;     // 229376 threads total
  if (idx < 131072) {
    int j = idx & 7, lane = (idx >> 3) & 63, vt = (idx >> 9) & 15,
        ut = (idx >> 13) & 7, h = (idx >> 16) & 1;
    int u = ut * 32 + (lane & 31);
    int v = vt * 16 + (lane >> 5) * 8 + j;
    int s = u * 256 + v;
    float ap = 1.f / (1.f + expf(-alp[s]));
    float an = 1.f / (1.f + expf(-aln[s]));
    bool  m  = ap > an;
    float val = h ? (m ? 0.f : -an) : (m ? ap : 0.f);   // neg sign folded
    A3[idx] = f2bf(val);
  } else {
    int k = idx - 131072;                       // 0 .. 98303
    int j = k & 7, lane = (k >> 3) & 63, kt = (k >> 9) & 7,
        ot = (k >> 12) & 3, hw = (k >> 14);     // hw = l*2+h
    int o = ot * 32 + (lane & 31);
    int d = kt * 16 + (lane >> 5) * 8 + j;
    const float* src = (hw & 1) ? wn : wp;
    W3[k] = f2bf(src[(hw >> 1) * 16384 + o * 128 + d]);
  }
}

__global__ __attribute__((amdgpu_flat_work_group_size(512, 512),
                          amdgpu_waves_per_eu(2, 2)))
void gnn_kernel(
    const float* __restrict__ X,
    const unsigned short* __restrict__ A3,
    const unsigned short* __restrict__ W3,
    const float* __restrict__ ln_g, const float* __restrict__ ln_b,
    const float* __restrict__ ro_g, const float* __restrict__ ro_b,
    float* __restrict__ out) {
  extern __shared__ char smem[];
  const int tid  = threadIdx.x;
  const int wid  = tid >> 6;
  const int lane = tid & 63;
  const int l31  = lane & 31;
  const int hi   = lane >> 5;
  const int b    = blockIdx.x;
  const int rg1  = wid >> 2, cg1 = wid & 3;    // GEMM1: v-tile(32), o-tile(32)
  const int rg2  = wid >> 1, cg2 = wid & 1;    // GEMM2: u-group(64), o-group(64)

  // ---- stage H = bf16(X[b]) into LDS ----
  {
    const float4* Xb = (const float4*)(X + (size_t)b * NNODE * DIMF);
#pragma unroll
    for (int i = 0; i < 16; ++i) {
      int idx = tid + i * 512;                 // 8192 float4 chunks
      int v = idx >> 5, d = (idx & 31) * 4;
      float4 f = Xb[idx];
      ushort4 p;
      p.x = f2bf(f.x); p.y = f2bf(f.y); p.z = f2bf(f.z); p.w = f2bf(f.w);
      *(ushort4*)(smem + haddr(v, d)) = p;
    }
  }
  __syncthreads();

  f32x16 acc[2][2];
  for (int l = 0; l < 3; ++l) {
#pragma unroll
    for (int mt = 0; mt < 2; ++mt)
#pragma unroll
      for (int nt = 0; nt < 2; ++nt)
#pragma unroll
        for (int r = 0; r < 16; ++r) acc[mt][nt][r] = 0.f;

    for (int h = 0; h < 2; ++h) {
      const unsigned short* Wf  = W3 + (((l * 2 + h) * 4 + cg1) * 8) * 512;
      const unsigned short* Ab0 = A3 + (size_t)((h * 8 + rg2 * 2 + 0) * 16) * 512;
      const unsigned short* Ab1 = A3 + (size_t)((h * 8 + rg2 * 2 + 1) * 16) * 512;

      // hoist this (l,h)'s W fragments into registers (reused by all 4 chunks)
      s16x8 wreg[8];
#pragma unroll
      for (int kt = 0; kt < 8; ++kt)
        wreg[kt] = *(const s16x8*)(Wf + kt * 512 + lane * 8);

      for (int c = 0; c < 4; ++c) {
        const int buf = (h * 4 + c) & 1;       // Gc double-buffer parity
        // ---- GEMM1: Gc[v in 64c..][o] = H @ W^T; one 32x32 tile per wave ----
        f32x16 gacc;
#pragma unroll
        for (int r = 0; r < 16; ++r) gacc[r] = 0.f;
        const int v0 = c * 64 + rg1 * 32 + l31;
#pragma unroll
        for (int kt = 0; kt < 8; ++kt) {       // K = d = 128
          s16x8 ha = *(const s16x8*)(smem + haddr(v0, kt * 16 + hi * 8));
          gacc = MFMA32(ha, wreg[kt], gacc);
        }
        // store Gc^T into buf (safe: last reader of this buf finished two
        // phases ago, guaranteed by the previous chunk's barrier)
        {
          const int og = cg1 * 32 + l31;       // C/D col = lane&31
#pragma unroll
          for (int rq = 0; rq < 4; ++rq) {     // rows v = (r&3)+8*(r>>2)+4*hi
            int vr = rg1 * 32 + rq * 8 + hi * 4;
            ushort4 p;
            p.x = f2bf(gacc[rq * 4 + 0]);
            p.y = f2bf(gacc[rq * 4 + 1]);
            p.z = f2bf(gacc[rq * 4 + 2]);
            p.w = f2bf(gacc[rq * 4 + 3]);
            *(ushort4*)(smem + gaddr(og, vr, buf)) = p;
          }
        }
        __syncthreads();                       // single barrier per chunk

        // ---- GEMM2: acc += Ac_h[u, 64c..] @ Gc[buf]; 64x64 tile per wave ----
#pragma unroll
        for (int kt = 0; kt < 4; ++kt) {       // K = v-chunk = 64
          s16x8 b0 = *(const s16x8*)(smem + gaddr(cg2 * 64 + l31,      kt * 16 + hi * 8, buf));
          s16x8 b1 = *(const s16x8*)(smem + gaddr(cg2 * 64 + 32 + l31, kt * 16 + hi * 8, buf));
          s16x8 a0 = *(const s16x8*)(Ab0 + (c * 4 + kt) * 512 + lane * 8);
          s16x8 a1 = *(const s16x8*)(Ab1 + (c * 4 + kt) * 512 + lane * 8);
          acc[0][0] = MFMA32(a0, b0, acc[0][0]);
          acc[0][1] = MFMA32(a0, b1, acc[0][1]);
          acc[1][0] = MFMA32(a1, b0, acc[1][0]);
          acc[1][1] = MFMA32(a1, b1, acc[1][1]);
        }
      } // chunks
    } // halves

    // ---- epilogue: exact GELU + LayerNorm -> H ----
    const float lg0 = ln_g[l * 128 + cg2 * 64 + l31];
    const float lg1 = ln_g[l * 128 + cg2 * 64 + 32 + l31];
    const float lb0 = ln_b[l * 128 + cg2 * 64 + l31];
    const float lb1 = ln_b[l * 128 + cg2 * 64 + 32 + l31];
#pragma unroll
    for (int mt = 0; mt < 2; ++mt)
#pragma unroll
      for (int nt = 0; nt < 2; ++nt)
#pragma unroll
        for (int r = 0; r < 16; ++r) {
          float x = acc[mt][nt][r];
          acc[mt][nt][r] = 0.5f * x * (1.f + erff(x * 0.70710678f));
        }
    // per-row partials over this wave's 64 cols -> (sum,sumsq), staged in
    // Gc buf 0 (its last readers, GEMM2 chunk 6, are past barrier 7)
    float w1 = 0.f, w2 = 0.f;
#pragma unroll
    for (int mt = 0; mt < 2; ++mt)
#pragma unroll
      for (int r = 0; r < 16; ++r) {
        float a0 = acc[mt][0][r], a1 = acc[mt][1][r];
        float s1 = a0 + a1;
        float s2 = a0 * a0 + a1 * a1;
#pragma unroll
        for (int m = 1; m < 32; m <<= 1) {     // reduce over 32 cols (in-half)
          s1 += __shfl_xor(s1, m);
          s2 += __shfl_xor(s2, m);
        }
        if (l31 == mt * 16 + r) { w1 = s1; w2 = s2; }
      }
    {
      int j  = l31;                            // j encodes (mt = j>>4, r = j&15)
      int uw = rg2 * 64 + (j >> 4) * 32 + (j & 3) + ((j >> 2) & 3) * 8 + hi * 4;
      float2 pw; pw.x = w1; pw.y = w2;
      *(float2*)(smem + HB + uw * 16 + cg2 * 8) = pw;
    }
    __syncthreads();
#pragma unroll
    for (int mt = 0; mt < 2; ++mt)
#pragma unroll
      for (int r = 0; r < 16; ++r) {
        int u = rg2 * 64 + mt * 32 + (r & 3) + ((r >> 2) & 3) * 8 + hi * 4;
        f32x4 rd = *(const f32x4*)(smem + HB + u * 16);    // broadcast read
        float mu  = (rd[0] + rd[2]) * (1.f / 128.f);
        float var = (rd[1] + rd[3]) * (1.f / 128.f) - mu * mu;
        float rs  = rsqrtf(var + 1e-5f);
        float y0 = (acc[mt][0][r] - mu) * rs * lg0 + lb0;
        float y1 = (acc[mt][1][r] - mu) * rs * lg1 + lb1;
        *(unsigned short*)(smem + haddr(u, cg2 * 64 + l31))      = f2bf(y0);
        *(unsigned short*)(smem + haddr(u, cg2 * 64 + 32 + l31)) = f2bf(y1);
      }
    __syncthreads();   // H fully updated before next layer / readout
  }

  // ---- readout: mean over nodes + final LN ----
  {
    int d   = tid & 127;
    int grp = tid >> 7;
    float s = 0.f;
    for (int v = grp * 64; v < grp * 64 + 64; ++v)
      s += bf2f(*(const unsigned short*)(smem + haddr(v, d)));
    float* red = (float*)(smem + HB);
    red[grp * 128 + d] = s;
    __syncthreads();
    if (tid < 128) {
      float hv = (red[tid] + red[128 + tid] + red[256 + tid] + red[384 + tid]) * (1.f / 256.f);
      red[512 + tid] = hv;
    }
    __syncthreads();
    if (tid < 64) {
      float a  = red[512 + tid];
      float b2 = red[512 + 64 + tid];
      float s1 = a + b2, s2 = a * a + b2 * b2;
#pragma unroll
      for (int m = 1; m < 64; m <<= 1) {
        s1 += __shfl_xor(s1, m);
        s2 += __shfl_xor(s2, m);
      }
      float mu  = s1 * (1.f / 128.f);
      float var = s2 * (1.f / 128.f) - mu * mu;
      float rs  = rsqrtf(var + 1e-5f);
      out[(size_t)b * 128 + tid]      = (a  - mu) * rs * ro_g[tid]      + ro_b[tid];
      out[(size_t)b * 128 + 64 + tid] = (b2 - mu) * rs * ro_g[64 + tid] + ro_b[64 + tid];
    }
  }
}

extern "C" void kernel_launch(void* const* d_in, const int* in_sizes, int n_in,
                              void* d_out, int out_size, void* d_ws, size_t ws_size,
                              hipStream_t stream) {
  const float* X   = (const float*)d_in[0];
  const float* alp = (const float*)d_in[1];
  const float* aln = (const float*)d_in[2];
  const float* wp  = (const float*)d_in[3];
  const float* wn  = (const float*)d_in[4];
  const float* lng = (const float*)d_in[5];
  const float* lnb = (const float*)d_in[6];
  const float* rog = (const float*)d_in[7];
  const float* rob = (const float*)d_in[8];
  float* out = (float*)d_out;

  unsigned short* A3 = (unsigned short*)d_ws;          // 131072 bf16 = 256 KB
  unsigned short* W3 = A3 + 131072;                    //  98304 bf16 = 192 KB

  (void)hipFuncSetAttribute(reinterpret_cast<const void*>(gnn_kernel),
                            hipFuncAttributeMaxDynamicSharedMemorySize, 131072);

  prep_kernel<<<448, 512, 0, stream>>>(alp, aln, wp, wn, A3, W3);
  gnn_kernel<<<2048, 512, 131072, stream>>>(X, A3, W3, lng, lnb, rog, rob, out);
}

// Round 6
// 1233.875 us; speedup vs baseline: 1.5021x; 1.0012x over previous
//
#include <hip/hip_runtime.h>
#include <math.h>

// HeterogeneousGNN fused kernel for MI355X (gfx950) — round 6.
// Structure identical to round 5 (H resident in LDS; W frags in regs; Gc
// double-buffered, one barrier/chunk; acc[2][2] f32x16). Round-5 diagnosis:
// amdgpu_waves_per_eu attr was silently IGNORED (VGPR stayed 128, 349 MB
// scratch writes). Empirical launch_bounds decode on this toolchain:
// (512,4)->64 VGPR, (512,2)->128 -> 2nd arg acts as min BLOCKS/CU.
// Fix: __launch_bounds__(512, 1) -> 2 waves/EU -> 256-VGPR cap; demand ~230
// fits -> zero spills, full-unroll ILP covers latency at 8 waves/CU.

typedef float  f32x4  __attribute__((ext_vector_type(4)));
typedef float  f32x16 __attribute__((ext_vector_type(16)));
typedef short  s16x8  __attribute__((ext_vector_type(8)));
typedef __bf16 bf16x8 __attribute__((ext_vector_type(8)));

#define NNODE 256
#define DIMF  128
#define HB    65536   // byte offset of Gc region in LDS (2 x 32768)

__device__ __forceinline__ unsigned short f2bf(float f) {
  unsigned int u = __builtin_bit_cast(unsigned int, f);
  u = (u + 0x7fffu + ((u >> 16) & 1u)) >> 16;   // round-to-nearest-even
  return (unsigned short)u;
}
__device__ __forceinline__ float bf2f(unsigned short h) {
  return __builtin_bit_cast(float, (unsigned int)h << 16);
}

// H: [256 v][128 d] bf16; XOR by (v&15) -> column reads 2-way (free).
__device__ __forceinline__ int haddr(int v, int d) {
  return v * 256 + ((d * 2) ^ ((v & 15) << 4));
}
// Gc^T: [128 o][row 256 B (64 v used)] bf16, double-buffered; 16-slot XOR by
// (o&15) -> column reads 2-way (free).
__device__ __forceinline__ int gaddr(int o, int vr, int buf) {
  return HB + buf * 32768 + o * 256 + ((vr * 2) ^ ((o & 15) << 4));
}

#define MFMA32(a, b, c) __builtin_amdgcn_mfma_f32_32x32x16_bf16( \
    __builtin_bit_cast(bf16x8, (a)), __builtin_bit_cast(bf16x8, (b)), (c), 0, 0, 0)

// ---- prep: build fragment-ordered A3 and W3 (bf16) ----
// A3[h][ut 0..7][vt 0..15][lane][j] = Ac_h[u=ut*32+(lane&31)][v=vt*16+(lane>>5)*8+j]
// W3[hw 0..5][ot 0..3][kt 0..7][lane][j] = W_hw[o=ot*32+(lane&31)][d=kt*16+(lane>>5)*8+j]
__global__ void prep_kernel(const float* __restrict__ alp, const float* __restrict__ aln,
                            const float* __restrict__ wp,  const float* __restrict__ wn,
                            unsigned short* __restrict__ A3, unsigned short* __restrict__ W3) {
  int idx = blockIdx.x * 512 + threadIdx.x;     // 229376 threads total
  if (idx < 131072) {
    int j = idx & 7, lane = (idx >> 3) & 63, vt = (idx >> 9) & 15,
        ut = (idx >> 13) & 7, h = (idx >> 16) & 1;
    int u = ut * 32 + (lane & 31);
    int v = vt * 16 + (lane >> 5) * 8 + j;
    int s = u * 256 + v;
    float ap = 1.f / (1.f + expf(-alp[s]));
    float an = 1.f / (1.f + expf(-aln[s]));
    bool  m  = ap > an;
    float val = h ? (m ? 0.f : -an) : (m ? ap : 0.f);   // neg sign folded
    A3[idx] = f2bf(val);
  } else {
    int k = idx - 131072;                       // 0 .. 98303
    int j = k & 7, lane = (k >> 3) & 63, kt = (k >> 9) & 7,
        ot = (k >> 12) & 3, hw = (k >> 14);     // hw = l*2+h
    int o = ot * 32 + (lane & 31);
    int d = kt * 16 + (lane >> 5) * 8 + j;
    const float* src = (hw & 1) ? wn : wp;
    W3[k] = f2bf(src[(hw >> 1) * 16384 + o * 128 + d]);
  }
}

__global__ __launch_bounds__(512, 1) void gnn_kernel(
    const float* __restrict__ X,
    const unsigned short* __restrict__ A3,
    const unsigned short* __restrict__ W3,
    const float* __restrict__ ln_g, const float* __restrict__ ln_b,
    const float* __restrict__ ro_g, const float* __restrict__ ro_b,
    float* __restrict__ out) {
  extern __shared__ char smem[];
  const int tid  = threadIdx.x;
  const int wid  = tid >> 6;
  const int lane = tid & 63;
  const int l31  = lane & 31;
  const int hi   = lane >> 5;
  const int b    = blockIdx.x;
  const int rg1  = wid >> 2, cg1 = wid & 3;    // GEMM1: v-tile(32), o-tile(32)
  const int rg2  = wid >> 1, cg2 = wid & 1;    // GEMM2: u-group(64), o-group(64)

  // ---- stage H = bf16(X[b]) into LDS ----
  {
    const float4* Xb = (const float4*)(X + (size_t)b * NNODE * DIMF);
#pragma unroll
    for (int i = 0; i < 16; ++i) {
      int idx = tid + i * 512;                 // 8192 float4 chunks
      int v = idx >> 5, d = (idx & 31) * 4;
      float4 f = Xb[idx];
      ushort4 p;
      p.x = f2bf(f.x); p.y = f2bf(f.y); p.z = f2bf(f.z); p.w = f2bf(f.w);
      *(ushort4*)(smem + haddr(v, d)) = p;
    }
  }
  __syncthreads();

  f32x16 acc[2][2];
  for (int l = 0; l < 3; ++l) {
#pragma unroll
    for (int mt = 0; mt < 2; ++mt)
#pragma unroll
      for (int nt = 0; nt < 2; ++nt)
#pragma unroll
        for (int r = 0; r < 16; ++r) acc[mt][nt][r] = 0.f;

    for (int h = 0; h < 2; ++h) {
      const unsigned short* Wf  = W3 + (((l * 2 + h) * 4 + cg1) * 8) * 512;
      const unsigned short* Ab0 = A3 + (size_t)((h * 8 + rg2 * 2 + 0) * 16) * 512;
      const unsigned short* Ab1 = A3 + (size_t)((h * 8 + rg2 * 2 + 1) * 16) * 512;

      // hoist this (l,h)'s W fragments into registers (reused by all 4 chunks)
      s16x8 wreg[8];
#pragma unroll
      for (int kt = 0; kt < 8; ++kt)
        wreg[kt] = *(const s16x8*)(Wf + kt * 512 + lane * 8);

      for (int c = 0; c < 4; ++c) {
        const int buf = (h * 4 + c) & 1;       // Gc double-buffer parity
        // ---- GEMM1: Gc[v in 64c..][o] = H @ W^T; one 32x32 tile per wave ----
        f32x16 gacc;
#pragma unroll
        for (int r = 0; r < 16; ++r) gacc[r] = 0.f;
        const int v0 = c * 64 + rg1 * 32 + l31;
#pragma unroll
        for (int kt = 0; kt < 8; ++kt) {       // K = d = 128
          s16x8 ha = *(const s16x8*)(smem + haddr(v0, kt * 16 + hi * 8));
          gacc = MFMA32(ha, wreg[kt], gacc);
        }
        // store Gc^T into buf (safe: last reader of this buf finished before
        // the PREVIOUS chunk's barrier)
        {
          const int og = cg1 * 32 + l31;       // C/D col = lane&31
#pragma unroll
          for (int rq = 0; rq < 4; ++rq) {     // rows v = (r&3)+8*(r>>2)+4*hi
            int vr = rg1 * 32 + rq * 8 + hi * 4;
            ushort4 p;
            p.x = f2bf(gacc[rq * 4 + 0]);
            p.y = f2bf(gacc[rq * 4 + 1]);
            p.z = f2bf(gacc[rq * 4 + 2]);
            p.w = f2bf(gacc[rq * 4 + 3]);
            *(ushort4*)(smem + gaddr(og, vr, buf)) = p;
          }
        }
        __syncthreads();                       // single barrier per chunk

        // ---- GEMM2: acc += Ac_h[u, 64c..] @ Gc[buf]; 64x64 tile per wave ----
#pragma unroll
        for (int kt = 0; kt < 4; ++kt) {       // K = v-chunk = 64
          s16x8 b0 = *(const s16x8*)(smem + gaddr(cg2 * 64 + l31,      kt * 16 + hi * 8, buf));
          s16x8 b1 = *(const s16x8*)(smem + gaddr(cg2 * 64 + 32 + l31, kt * 16 + hi * 8, buf));
          s16x8 a0 = *(const s16x8*)(Ab0 + (c * 4 + kt) * 512 + lane * 8);
          s16x8 a1 = *(const s16x8*)(Ab1 + (c * 4 + kt) * 512 + lane * 8);
          acc[0][0] = MFMA32(a0, b0, acc[0][0]);
          acc[0][1] = MFMA32(a0, b1, acc[0][1]);
          acc[1][0] = MFMA32(a1, b0, acc[1][0]);
          acc[1][1] = MFMA32(a1, b1, acc[1][1]);
        }
      } // chunks
    } // halves

    // ---- epilogue: exact GELU + LayerNorm -> H ----
    const float lg0 = ln_g[l * 128 + cg2 * 64 + l31];
    const float lg1 = ln_g[l * 128 + cg2 * 64 + 32 + l31];
    const float lb0 = ln_b[l * 128 + cg2 * 64 + l31];
    const float lb1 = ln_b[l * 128 + cg2 * 64 + 32 + l31];
#pragma unroll
    for (int mt = 0; mt < 2; ++mt)
#pragma unroll
      for (int nt = 0; nt < 2; ++nt)
#pragma unroll
        for (int r = 0; r < 16; ++r) {
          float x = acc[mt][nt][r];
          acc[mt][nt][r] = 0.5f * x * (1.f + erff(x * 0.70710678f));
        }
    // per-row partials over this wave's 64 cols -> (sum,sumsq), staged in
    // Gc region (all GEMM2 reads are behind the last chunk barrier)
    float w1 = 0.f, w2 = 0.f;
#pragma unroll
    for (int mt = 0; mt < 2; ++mt)
#pragma unroll
      for (int r = 0; r < 16; ++r) {
        float a0 = acc[mt][0][r], a1 = acc[mt][1][r];
        float s1 = a0 + a1;
        float s2 = a0 * a0 + a1 * a1;
#pragma unroll
        for (int m = 1; m < 32; m <<= 1) {     // reduce over 32 cols (in-half)
          s1 += __shfl_xor(s1, m);
          s2 += __shfl_xor(s2, m);
        }
        if (l31 == mt * 16 + r) { w1 = s1; w2 = s2; }
      }
    {
      int j  = l31;                            // j encodes (mt = j>>4, r = j&15)
      int uw = rg2 * 64 + (j >> 4) * 32 + (j & 3) + ((j >> 2) & 3) * 8 + hi * 4;
      float2 pw; pw.x = w1; pw.y = w2;
      *(float2*)(smem + HB + uw * 16 + cg2 * 8) = pw;
    }
    __syncthreads();
#pragma unroll
    for (int mt = 0; mt < 2; ++mt)
#pragma unroll
      for (int r = 0; r < 16; ++r) {
        int u = rg2 * 64 + mt * 32 + (r & 3) + ((r >> 2) & 3) * 8 + hi * 4;
        f32x4 rd = *(const f32x4*)(smem + HB + u * 16);    // broadcast read
        float mu  = (rd[0] + rd[2]) * (1.f / 128.f);
        float var = (rd[1] + rd[3]) * (1.f / 128.f) - mu * mu;
        float rs  = rsqrtf(var + 1e-5f);
        float y0 = (acc[mt][0][r] - mu) * rs * lg0 + lb0;
        float y1 = (acc[mt][1][r] - mu) * rs * lg1 + lb1;
        *(unsigned short*)(smem + haddr(u, cg2 * 64 + l31))      = f2bf(y0);
        *(unsigned short*)(smem + haddr(u, cg2 * 64 + 32 + l31)) = f2bf(y1);
      }
    __syncthreads();   // H fully updated before next layer / readout
  }

  // ---- readout: mean over nodes + final LN ----
  {
    int d   = tid & 127;
    int grp = tid >> 7;
    float s = 0.f;
    for (int v = grp * 64; v < grp * 64 + 64; ++v)
      s += bf2f(*(const unsigned short*)(smem + haddr(v, d)));
    float* red = (float*)(smem + HB);
    red[grp * 128 + d] = s;
    __syncthreads();
    if (tid < 128) {
      float hv = (red[tid] + red[128 + tid] + red[256 + tid] + red[384 + tid]) * (1.f / 256.f);
      red[512 + tid] = hv;
    }
    __syncthreads();
    if (tid < 64) {
      float a  = red[512 + tid];
      float b2 = red[512 + 64 + tid];
      float s1 = a + b2, s2 = a * a + b2 * b2;
#pragma unroll
      for (int m = 1; m < 64; m <<= 1) {
        s1 += __shfl_xor(s1, m);
        s2 += __shfl_xor(s2, m);
      }
      float mu  = s1 * (1.f / 128.f);
      float var = s2 * (1.f / 128.f) - mu * mu;
      float rs  = rsqrtf(var + 1e-5f);
      out[(size_t)b * 128 + tid]      = (a  - mu) * rs * ro_g[tid]      + ro_b[tid];
      out[(size_t)b * 128 + 64 + tid] = (b2 - mu) * rs * ro_g[64 + tid] + ro_b[64 + tid];
    }
  }
}

extern "C" void kernel_launch(void* const* d_in, const int* in_sizes, int n_in,
                              void* d_out, int out_size, void* d_ws, size_t ws_size,
                              hipStream_t stream) {
  const float* X   = (const float*)d_in[0];
  const float* alp = (const float*)d_in[1];
  const float* aln = (const float*)d_in[2];
  const float* wp  = (const float*)d_in[3];
  const float* wn  = (const float*)d_in[4];
  const float* lng = (const float*)d_in[5];
  const float* lnb = (const float*)d_in[6];
  const float* rog = (const float*)d_in[7];
  const float* rob = (const float*)d_in[8];
  float* out = (float*)d_out;

  unsigned short* A3 = (unsigned short*)d_ws;          // 131072 bf16 = 256 KB
  unsigned short* W3 = A3 + 131072;                    //  98304 bf16 = 192 KB

  (void)hipFuncSetAttribute(reinterpret_cast<const void*>(gnn_kernel),
                            hipFuncAttributeMaxDynamicSharedMemorySize, 131072);

  prep_kernel<<<448, 512, 0, stream>>>(alp, aln, wp, wn, A3, W3);
  gnn_kernel<<<2048, 512, 131072, stream>>>(X, A3, W3, lng, lnb, rog, rob, out);
}